// Round 1
// baseline (362.572 us; speedup 1.0000x reference)
//
#include <hip/hip_runtime.h>
#include <hip/hip_bf16.h>
#include <hip/hip_fp8.h>
#include <math.h>

// Problem constants (fixed by setup_inputs): B=4096, D=512, V=50000.
#define B_ROWS 4096
#define DIMS   512
#define V_ROWS 50000
#define V_PAD  50048            // 391 * 128
#define NTILES 391              // V_PAD / 128
#define NT_PAD 392              // cands row stride (ulonglong2 units)
#define MTILES 32               // B_ROWS / 128
#define BKB    128              // K-bytes (fp8 elems) staged per iteration = one K=128 MFMA
#define NROWS_ALL 54144         // V_PAD + B_ROWS (fused normalize grid-stride range)
#define EPSF   1e-8f
#define QSCALE 64.0f            // row pre-scale before fp8 quant (dodges e4m3 subnormals)
#define SCALE1 0x7F7F7F7F       // E8M0 unity scale broadcast to all 4 bytes

typedef float f32x4 __attribute__((ext_vector_type(4)));
typedef int   i32x4 __attribute__((ext_vector_type(4)));
typedef int   i32x8 __attribute__((ext_vector_type(8)));
typedef unsigned long long u64;

// fp8 e4m3 (OCP) pack of 4 floats -> u32, bytes little-endian in k order
__device__ __forceinline__ unsigned int pk4_fp8(float a, float b, float c, float d) {
#if __has_builtin(__builtin_amdgcn_cvt_pk_fp8_f32)
  int w = __builtin_amdgcn_cvt_pk_fp8_f32(a, b, 0, false);   // bytes 0,1
  w = __builtin_amdgcn_cvt_pk_fp8_f32(c, d, w, true);        // bytes 2,3
  return (unsigned int)w;
#else
  __hip_fp8_e4m3 qa(a), qb(b), qc(c), qd(d);
  return (unsigned int)qa.__x | ((unsigned int)qb.__x << 8) |
         ((unsigned int)qc.__x << 16) | ((unsigned int)qd.__x << 24);
#endif
}

// async global->LDS, 16B per lane. LDS dest is wave-uniform base + lane*16.
__device__ __forceinline__ void lds_load16(const void* g, void* l) {
  __builtin_amdgcn_global_load_lds(
      (const __attribute__((address_space(1))) void*)g,
      (__attribute__((address_space(3))) void*)l, 16, 0, 0);
}

// ---------------------------------------------------------------------------
// Packed top-2 keys. key = (sortable(v) << 32) | ~col.
// u64 compare == (value desc, col asc) — matches jax top_k first-occurrence
// tie-break exactly. Keys within a row are always distinct (distinct cols).
// ---------------------------------------------------------------------------
__device__ __forceinline__ u64 pack_key(float v, int col) {
  unsigned int u = __float_as_uint(v);
  unsigned int s = u ^ ((unsigned int)((int)u >> 31) | 0x80000000u);
  return ((u64)s << 32) | (unsigned int)(~col);
}
__device__ __forceinline__ int key_col(u64 k) {
  return (int)(~(unsigned int)k);
}
// merge sorted pair (a0>=a1) into running sorted top-2 (k0>=k1)
__device__ __forceinline__ void kmerge(u64& k0, u64& k1, u64 a0, u64 a1) {
  bool bt = a0 > k0;
  u64 lo = bt ? k0 : a0;        // loser of the top comparison
  u64 hi = bt ? a1 : k1;        // runner-up of the winner's pair
  k0 = bt ? a0 : k0;
  k1 = hi > lo ? hi : lo;
}

// ---------------------------------------------------------------------------
// K1 (fused): row-normalize fp32 -> fp8 e4m3 (scaled by QSCALE) for BOTH
// veclist (rows [0,V_PAD), pad rows zero-filled) and input (rows
// [V_PAD, V_PAD+B_ROWS)). One WAVE per row (64 lanes x 8 elems), grid-stride.
// ---------------------------------------------------------------------------
__global__ __launch_bounds__(256)
void normalize_rows_kernel(const float* __restrict__ vsrc, const float* __restrict__ isrc,
                           unsigned char* __restrict__ vdst, unsigned char* __restrict__ idst) {
  const int l = threadIdx.x & 63;
  const int gw = (blockIdx.x * 256 + threadIdx.x) >> 6;
  const int nw = (gridDim.x * 256) >> 6;
  for (int row = gw; row < NROWS_ALL; row += nw) {
    const float* src;
    unsigned char* dst;
    if (row < V_PAD) {
      if (row >= V_ROWS) {           // zero-fill pad rows
        *(uint2*)&vdst[(size_t)row * DIMS + l * 8] = make_uint2(0u, 0u);
        continue;
      }
      src = vsrc + (size_t)row * DIMS;
      dst = vdst + (size_t)row * DIMS;
    } else {
      src = isrc + (size_t)(row - V_PAD) * DIMS;
      dst = idst + (size_t)(row - V_PAD) * DIMS;
    }
    float4 v0 = ((const float4*)src)[l * 2];
    float4 v1 = ((const float4*)src)[l * 2 + 1];
    float ss = v0.x * v0.x + v0.y * v0.y + v0.z * v0.z + v0.w * v0.w
             + v1.x * v1.x + v1.y * v1.y + v1.z * v1.z + v1.w * v1.w;
    #pragma unroll
    for (int d = 1; d < 64; d <<= 1) ss += __shfl_xor(ss, d);
    float s = QSCALE / fmaxf(sqrtf(ss), EPSF);
    uint2 o;
    o.x = pk4_fp8(v0.x * s, v0.y * s, v0.z * s, v0.w * s);
    o.y = pk4_fp8(v1.x * s, v1.y * s, v1.z * s, v1.w * s);
    *(uint2*)&dst[l * 8] = o;
  }
}

// ---------------------------------------------------------------------------
// K3: MX-scaled fp8 MFMA GEMM (mfma_scale_f32_16x16x128_f8f6f4, unity E8M0
// scales). BKB=128 staged bytes = one K=128 MFMA per acc per k0 (4 k0 iters,
// 8 barriers). XOR-8 swizzled LDS; fragment reads are 2x ds_read_b128 per
// operand tile. K-loop byte-identical to the 450 us verified version.
//
// Occupancy (r5/r6 measured): ~96 VGPR + 64 AGPR = ~160 unified regs;
// (256,3) caps at 170 -> fits, 3 blocks/CU (LDS 32KBx3=96KB, regs fit).
//
// Epilogue REWRITTEN this round (r7 theory: old 256-shuffle butterfly cost
// ~3500 cy/wave > the wave's entire 2200 cy of MFMA):
//   per (tr,reg): scan 4 tc -> sorted top-2 packed-u64 pair -> one
//   ds_write_b128 into a 32KB LDS scratch that REUSES the dead As/Bs
//   (union); then 4 threads/row serially merge 8 sorted pairs each
//   (read index XOR-swizzled by slot&7 to break the uniform-bank pattern)
//   + 2-stage quad-shuffle combine. Two passes over tr to fit 32 KB.
//   cands now stores packed key pairs; indices are unpacked in finalize.
// ---------------------------------------------------------------------------
__global__ __launch_bounds__(256, 3)
void gemm_top2_kernel(const unsigned char* __restrict__ A8,
                      const unsigned char* __restrict__ B8,
                      ulonglong2* __restrict__ cands) {
  __shared__ __align__(16) unsigned char smem[2 * 128 * BKB];   // 32 KB: As | Bs
  unsigned char* const As = smem;
  unsigned char* const Bs = smem + 128 * BKB;

  const int bid = blockIdx.x;
  const int mt = bid & 31;        // 32 consecutive blocks share the B-tile
  const int nt = bid >> 5;        // 0..390
  const int m0 = mt * 128, n0 = nt * 128;

  const int tid = threadIdx.x;
  const int w = tid >> 6, l = tid & 63;
  const int wr = w >> 1, wc = w & 1;     // 2x2 wave grid, 64x64 per wave
  const int lq = l >> 4, lr = l & 15;
  const int h = lr & 7;                  // XOR swizzle key

  // fragment slot offsets (constant across k0)
  const int s0 = ((2 * lq) ^ h) * 16;    // byte offset of chunk 2lq
  const int s1 = ((2 * lq + 1) ^ h) * 16;

  f32x4 acc[4][4] = {};

  for (int k0 = 0; k0 < DIMS; k0 += BKB) {
    // stage A,B fp8 tiles: 1024 16B-chunks each (128 rows x 8 chunks)
    #pragma unroll
    for (int it = 0; it < 4; ++it) {
      const int chunk = it * 256 + w * 64 + l;   // 0..1023
      const int row = chunk >> 3, c = chunk & 7;
      const int gc = c ^ (row & 7);              // swizzled global chunk
      lds_load16(A8 + (size_t)(m0 + row) * DIMS + k0 + gc * 16,
                 &As[(it * 256 + w * 64) * 16]);
      lds_load16(B8 + (size_t)(n0 + row) * DIMS + k0 + gc * 16,
                 &Bs[(it * 256 + w * 64) * 16]);
    }
    __syncthreads();

    // B fragments for all 4 col-tiles (32 VGPRs live)
    i32x8 bf[4];
    #pragma unroll
    for (int tc = 0; tc < 4; ++tc) {
      const int rb = (wc * 64 + tc * 16 + lr) * BKB;
      i32x4 blo = *(const i32x4*)&Bs[rb + s0];
      i32x4 bhi = *(const i32x4*)&Bs[rb + s1];
      bf[tc] = __builtin_shufflevector(blo, bhi, 0, 1, 2, 3, 4, 5, 6, 7);
    }
    // A fragments one tile at a time; 4 MFMAs each
    #pragma unroll
    for (int tr = 0; tr < 4; ++tr) {
      const int ra = (wr * 64 + tr * 16 + lr) * BKB;
      i32x4 alo = *(const i32x4*)&As[ra + s0];
      i32x4 ahi = *(const i32x4*)&As[ra + s1];
      i32x8 af = __builtin_shufflevector(alo, ahi, 0, 1, 2, 3, 4, 5, 6, 7);
      #pragma unroll
      for (int tc = 0; tc < 4; ++tc)
        acc[tr][tc] = __builtin_amdgcn_mfma_scale_f32_16x16x128_f8f6f4(
            af, bf[tc], acc[tr][tc],
            0, 0,                 // cbsz = fp8(e4m3), blgp = fp8(e4m3)
            0, SCALE1,            // scale_a opsel, scale_a (unity all bytes)
            0, SCALE1);           // scale_b opsel, scale_b
    }
    __syncthreads();
  }

  // ---- epilogue: per-row top-2 over this block's 128 cols (packed u64) ----
  // C/D layout: row = (lane>>4)*4 + reg, col = lane&15 (per 16x16 tile).
  // LDS scratch overlays As|Bs: 64 slots x 32 entries x 16 B = 32 KB exactly.
  // slot = wr*32 + trh*16 + lq*4 + reg  ->  row = (slot>>5)*64 + p*32 + (slot&31)
  ulonglong2 (*ep)[32] = (ulonglong2(*)[32])smem;
  const int colbase = n0 + wc * 64 + lr;

  #pragma unroll
  for (int p = 0; p < 2; ++p) {
    #pragma unroll
    for (int trh = 0; trh < 2; ++trh) {
      const int tr = p * 2 + trh;
      #pragma unroll
      for (int rg = 0; rg < 4; ++rg) {
        u64 kk[4];
        #pragma unroll
        for (int tc = 0; tc < 4; ++tc) {
          const int col = colbase + tc * 16;
          const float v = (col < V_ROWS) ? acc[tr][tc][rg] : -INFINITY;  // pad-col mask
          kk[tc] = pack_key(v, col);
        }
        const bool s01 = kk[0] > kk[1];
        u64 a0 = s01 ? kk[0] : kk[1], a1 = s01 ? kk[1] : kk[0];
        const bool s23 = kk[2] > kk[3];
        u64 b0 = s23 ? kk[2] : kk[3], b1 = s23 ? kk[3] : kk[2];
        kmerge(a0, a1, b0, b1);                       // sorted top-2 of 4 tc
        const int slot = wr * 32 + trh * 16 + lq * 4 + rg;
        ep[slot][(wc * 16 + lr) ^ (slot & 7)] = make_ulonglong2(a0, a1);
      }
    }
    __syncthreads();
    {
      // 4 threads per row merge 8 sorted pairs each, then quad-combine.
      const int ms = tid >> 2, q = tid & 3;
      u64 k0 = 0, k1 = 0;                             // 0 < any real key
      #pragma unroll
      for (int k = 0; k < 8; ++k) {
        ulonglong2 e = ep[ms][(q * 8 + k) ^ (ms & 7)];
        kmerge(k0, k1, e.x, e.y);
      }
      #pragma unroll
      for (int d = 1; d < 4; d <<= 1) {
        u64 o0 = __shfl_xor(k0, d), o1 = __shfl_xor(k1, d);
        kmerge(k0, k1, o0, o1);
      }
      if (q == 0) {
        const int row = (ms >> 5) * 64 + p * 32 + (ms & 31);
        // transposed layout: [row][tile] so finalize reads are coalesced
        cands[(size_t)(m0 + row) * NT_PAD + nt] = make_ulonglong2(k0, k1);
      }
    }
    __syncthreads();   // LDS reused by next pass
  }
}

// ---------------------------------------------------------------------------
// K5: per-row final. Merge 391 packed tile candidate pairs -> global top-2
// indices (u64 compares only; values never unpacked), then recompute
// d_pos / d_neg exactly in fp32 from the original inputs. Per-row contrib,
// no single-address atomics.
// ---------------------------------------------------------------------------
__global__ __launch_bounds__(256)
void finalize_kernel(const float* __restrict__ input, const float* __restrict__ target,
                     const float* __restrict__ veclist, const ulonglong2* __restrict__ cands,
                     float* __restrict__ contrib) {
  const int b = blockIdx.x;
  const int t = threadIdx.x;
  __shared__ ulonglong2 wpair[4];
  __shared__ int sidx[2];
  __shared__ float red[4][7];
  __shared__ int reda[4];

  // phase A: global top-2 across tiles (coalesced: cands[b][nt])
  u64 k0 = 0, k1 = 0;
  for (int nt = t; nt < NTILES; nt += 256) {
    ulonglong2 c = cands[(size_t)b * NT_PAD + nt];
    kmerge(k0, k1, c.x, c.y);
  }
  #pragma unroll
  for (int d = 1; d < 64; d <<= 1) {
    u64 o0 = __shfl_xor(k0, d), o1 = __shfl_xor(k1, d);
    kmerge(k0, k1, o0, o1);
  }
  if ((t & 63) == 0) wpair[t >> 6] = make_ulonglong2(k0, k1);
  __syncthreads();
  if (t == 0) {
    u64 m0k = wpair[0].x, m1k = wpair[0].y;
    for (int wd = 1; wd < 4; ++wd) kmerge(m0k, m1k, wpair[wd].x, wpair[wd].y);
    sidx[0] = key_col(m0k);
    sidx[1] = key_col(m1k);
  }
  __syncthreads();
  const int idx0 = sidx[0], idx1 = sidx[1];

  // phase B: exact fp32 dot products / norms
  const float2* xin = (const float2*)(input  + (size_t)b * DIMS);
  const float2* xtg = (const float2*)(target + (size_t)b * DIMS);
  const float2* xv0 = (const float2*)(veclist + (size_t)idx0 * DIMS);
  const float2* xv1 = (const float2*)(veclist + (size_t)idx1 * DIMS);
  float2 xi = xin[t], tg = xtg[t], a0 = xv0[t], a1 = xv1[t];
  float s[7];
  s[0] = xi.x * xi.x + xi.y * xi.y;
  s[1] = tg.x * tg.x + tg.y * tg.y;
  s[2] = xi.x * tg.x + xi.y * tg.y;
  s[3] = a0.x * a0.x + a0.y * a0.y;
  s[4] = xi.x * a0.x + xi.y * a0.y;
  s[5] = a1.x * a1.x + a1.y * a1.y;
  s[6] = xi.x * a1.x + xi.y * a1.y;
  bool eq = (a0.x == tg.x) && (a0.y == tg.y);
  int weq = __all(eq);
  #pragma unroll
  for (int k = 0; k < 7; ++k)
    #pragma unroll
    for (int d = 1; d < 64; d <<= 1) s[k] += __shfl_xor(s[k], d);
  if ((t & 63) == 0) {
    #pragma unroll
    for (int k = 0; k < 7; ++k) red[t >> 6][k] = s[k];
    reda[t >> 6] = weq;
  }
  __syncthreads();
  if (t == 0) {
    float r[7];
    #pragma unroll
    for (int k = 0; k < 7; ++k)
      r[k] = red[0][k] + red[1][k] + red[2][k] + red[3][k];
    bool eq0 = reda[0] && reda[1] && reda[2] && reda[3];
    float na  = fmaxf(sqrtf(r[0]), EPSF);
    float ntg = fmaxf(sqrtf(r[1]), EPSF);
    float simp = r[2] / (na * ntg);
    float d_pos = sqrtf(fmaxf(2.0f * (1.0f - simp), 1e-12f));
    float nn = eq0 ? fmaxf(sqrtf(r[5]), EPSF) : fmaxf(sqrtf(r[3]), EPSF);
    float dn = eq0 ? r[6] : r[4];
    float simn = dn / (na * nn);
    float d_neg = sqrtf(fmaxf(2.0f * (1.0f - simn), 1e-12f));
    float margin = 0.5f + d_pos - d_neg;          // GAMMA + d_pos - d_neg
    contrib[b] = 2.0f * fmaxf(margin, 0.0f) * (1.0f / (float)B_ROWS);  // RANK=2
  }
}

// ---------------------------------------------------------------------------
// K6: sum 4096 per-row contributions -> out[0]. One block, no atomics.
// ---------------------------------------------------------------------------
__global__ __launch_bounds__(256)
void reduce_kernel(const float* __restrict__ contrib, float* __restrict__ out) {
  const int t = threadIdx.x;
  __shared__ float wsum[4];
  float s = 0.0f;
  for (int i = t; i < B_ROWS; i += 256) s += contrib[i];
  #pragma unroll
  for (int d = 1; d < 64; d <<= 1) s += __shfl_xor(s, d);
  if ((t & 63) == 0) wsum[t >> 6] = s;
  __syncthreads();
  if (t == 0) out[0] = wsum[0] + wsum[1] + wsum[2] + wsum[3];
}

// ---------------------------------------------------------------------------
// Workspace layout (bytes):
//   vnn  fp8 [50048][512]          @ 0          : 25,624,576
//   inn  fp8 [4096][512]           @ 25,624,576 :  2,097,152
//   cands ulonglong2 [4096][392]   @ 27,721,728 : 25,690,112
//   contrib float [4096]           @ 53,411,840 :     16,384   (total ~53.4 MB)
// ---------------------------------------------------------------------------
extern "C" void kernel_launch(void* const* d_in, const int* in_sizes, int n_in,
                              void* d_out, int out_size, void* d_ws, size_t ws_size,
                              hipStream_t stream) {
  const float* input   = (const float*)d_in[0];
  const float* target  = (const float*)d_in[1];
  const float* veclist = (const float*)d_in[2];
  float* out = (float*)d_out;
  char* ws = (char*)d_ws;
  unsigned char* vnn = (unsigned char*)ws;
  unsigned char* inn = (unsigned char*)(ws + 25624576);
  ulonglong2* cands = (ulonglong2*)(ws + 27721728);
  float* contrib = (float*)(ws + 53411840);

  normalize_rows_kernel<<<2048, 256, 0, stream>>>(veclist, input, vnn, inn);
  gemm_top2_kernel<<<MTILES * NTILES, 256, 0, stream>>>(inn, vnn, cands);
  finalize_kernel<<<B_ROWS, 256, 0, stream>>>(input, target, veclist, cands, contrib);
  reduce_kernel<<<1, 256, 0, stream>>>(contrib, out);
}